// Round 2
// baseline (371.053 us; speedup 1.0000x reference)
//
#include <hip/hip_runtime.h>
#include <hip/hip_bf16.h>

typedef __attribute__((ext_vector_type(8))) short short8;
typedef __attribute__((ext_vector_type(4))) float f32x4;

namespace {
constexpr int D    = 128;
constexpr int SEQ  = 512;
constexpr int NV   = 100000;
constexpr int NN   = 2048;
constexpr int KC   = 64;                     // keys per LDS chunk
constexpr int CHUNK_B = KC * D * 2;          // 16384 B
constexpr int NCHUNK  = (NV + KC - 1) / KC;  // 1563
constexpr int CPS     = 13;                  // chunks per V-slice
constexpr int NSLICE  = (NCHUNK + CPS - 1) / CPS;  // 121
constexpr float LOG2E = 1.4426950408889634f;
constexpr float EPSN  = 1e-12f;
}

// ---------------------------------------------------------------------------
// Prep: normalize keys -> bf16 Kn[V][128]; gather+normalize queries scaled by
// log2(e) -> bf16 Qn[N][128]. One wave per row.
// ---------------------------------------------------------------------------
__global__ void prep_kernel(const float* __restrict__ qemb,
                            const float* __restrict__ kemb,
                            const int*   __restrict__ loc,
                            __hip_bfloat16* __restrict__ Kn,
                            __hip_bfloat16* __restrict__ Qn)
{
    int wave = (blockIdx.x * blockDim.x + threadIdx.x) >> 6;
    int lane = threadIdx.x & 63;
    if (wave >= NV + NN) return;

    const float* src;
    __hip_bfloat16* dst;
    float extra;
    if (wave < NV) {
        src = kemb + (size_t)wave * D;
        dst = Kn + (size_t)wave * D;
        extra = 1.0f;
    } else {
        int n = wave - NV;
        int b = loc[2 * n], s = loc[2 * n + 1];
        src = qemb + ((size_t)b * SEQ + s) * D;
        dst = Qn + (size_t)n * D;
        extra = LOG2E;
    }
    float2 v = *(const float2*)(src + lane * 2);
    float ss = v.x * v.x + v.y * v.y;
    #pragma unroll
    for (int m = 1; m < 64; m <<= 1) ss += __shfl_xor(ss, m);
    float inv = extra / fmaxf(sqrtf(ss), EPSN);
    __hip_bfloat162 o;
    o.x = __float2bfloat16(v.x * inv);
    o.y = __float2bfloat16(v.y * inv);
    *(__hip_bfloat162*)(dst + lane * 2) = o;
}

// ---------------------------------------------------------------------------
// Main: per block, 256 Q-rows (4 waves x 64 rows, A-frags in registers),
// stream keys through double-buffered 64-key LDS chunks staged via
// global_load_lds (linear LDS dest, inverse-swizzled global source).
// Read-side XOR swizzle: phys = logical ^ ((keyrow&7)<<4).
// rowsum += exp2(logit) -> fixed-shift LSE (|logit|<=log2e, no max needed).
// ---------------------------------------------------------------------------
__global__ __launch_bounds__(256, 4)
void lse_main(const __hip_bfloat16* __restrict__ Kn,
              const __hip_bfloat16* __restrict__ Qn,
              float* __restrict__ sums)
{
    __shared__ char lds[2 * CHUNK_B];   // 32 KB -> 4 blocks/CU
    const int tid  = threadIdx.x;
    const int lane = tid & 63;
    const int lr   = lane & 15;
    const int lh   = lane >> 4;
    const int w    = tid >> 6;
    const int mblk  = blockIdx.x;   // 0..7
    const int slice = blockIdx.y;   // 0..NSLICE-1

    const int chunk0 = slice * CPS;
    const int nch = min(CPS, NCHUNK - chunk0);
    const int m0 = mblk * 256 + w * 64;
    const char* kbase = (const char*)Kn;

    // async stage of chunk c into buffer bi: LDS linear, source pre-swizzled
    auto stage = [&](int c, int bi) {
        const int keybase = (chunk0 + c) * KC;
        #pragma unroll
        for (int r = 0; r < 4; ++r) {
            const int i   = w * 4 + r;          // 1KB-slab index, wave-uniform
            const int kic = i * 4 + lh;         // key row within chunk (per-lane)
            const int key = min(keybase + kic, NV - 1);
            const int sb  = (lr ^ (kic & 7)) << 4;   // inverse-swizzled byte-in-row
            const char* g = kbase + (size_t)key * 256 + sb;
            const char* l = lds + bi * CHUNK_B + i * 1024;  // wave-uniform base
            __builtin_amdgcn_global_load_lds(
                (const __attribute__((address_space(1))) void*)g,
                (__attribute__((address_space(3))) void*)l, 16, 0, 0);
        }
    };

    stage(0, 0);   // prologue: in flight while we fetch Q fragments

    // A-operand (Q) fragments: rows m0+rg*16+lr, k = ds*32 + lh*8 .. +8
    short8 qf[4][4];
    #pragma unroll
    for (int rg = 0; rg < 4; ++rg)
        #pragma unroll
        for (int ds = 0; ds < 4; ++ds)
            qf[rg][ds] = *(const short8*)((const short*)Qn +
                          (size_t)(m0 + rg * 16 + lr) * D + ds * 32 + lh * 8);

    float rowsum[4][4] = {};
    __syncthreads();   // drains prologue glds (vmcnt) + barrier

    int cur = 0;
    for (int c = 0; c < nch; ++c) {
        if (c + 1 < nch) stage(c + 1, cur ^ 1);   // issue early (T14 / T3-min)

        const char* buf = lds + cur * CHUNK_B;
        const int vbase = (chunk0 + c) * KC;
        const bool full = (vbase + KC <= NV);
        #pragma unroll
        for (int kg = 0; kg < 4; ++kg) {
            const int kic = kg * 16 + lr;       // key row within chunk
            const int rx  = (kic & 7) << 4;
            f32x4 acc[4] = {{0,0,0,0},{0,0,0,0},{0,0,0,0},{0,0,0,0}};
            #pragma unroll
            for (int ds2 = 0; ds2 < 4; ++ds2) {
                short8 bf = *(const short8*)(buf +
                              ((kic * 256 + ds2 * 64 + lh * 16) ^ rx));
                #pragma unroll
                for (int rg = 0; rg < 4; ++rg)
                    acc[rg] = __builtin_amdgcn_mfma_f32_16x16x32_bf16(
                                  qf[rg][ds2], bf, acc[rg], 0, 0, 0);
            }
            if (full) {
                #pragma unroll
                for (int rg = 0; rg < 4; ++rg)
                    #pragma unroll
                    for (int j = 0; j < 4; ++j)
                        rowsum[rg][j] += __builtin_amdgcn_exp2f(acc[rg][j]);
            } else {
                const bool ok = (vbase + kic) < NV;   // col = lr on output
                #pragma unroll
                for (int rg = 0; rg < 4; ++rg)
                    #pragma unroll
                    for (int j = 0; j < 4; ++j)
                        rowsum[rg][j] += ok ? __builtin_amdgcn_exp2f(acc[rg][j]) : 0.f;
            }
        }
        __syncthreads();   // drains stage's vmcnt + protects buffer swap
        cur ^= 1;
    }

    // reduce partial sums across the 16 column-lanes, one atomic per row
    #pragma unroll
    for (int rg = 0; rg < 4; ++rg)
        #pragma unroll
        for (int j = 0; j < 4; ++j) {
            float v = rowsum[rg][j];
            v += __shfl_xor(v, 1);
            v += __shfl_xor(v, 2);
            v += __shfl_xor(v, 4);
            v += __shfl_xor(v, 8);
            if (lr == 0)
                atomicAdd(&sums[m0 + rg * 16 + lh * 4 + j], v);
        }
}

// ---------------------------------------------------------------------------
// tgt[n] = <q_n, k_label>/(|q_n||k_label|) in full fp32. One wave per n.
// ---------------------------------------------------------------------------
__global__ void tgt_kernel(const float* __restrict__ qemb,
                           const float* __restrict__ kemb,
                           const int*   __restrict__ loc,
                           const int*   __restrict__ labels,
                           float* __restrict__ tgt)
{
    int n = (blockIdx.x * blockDim.x + threadIdx.x) >> 6;
    int lane = threadIdx.x & 63;
    if (n >= NN) return;
    int b = loc[2 * n], s = loc[2 * n + 1];
    const float* q = qemb + ((size_t)b * SEQ + s) * D;
    const float* k = kemb + (size_t)labels[n] * D;
    float2 qv = *(const float2*)(q + lane * 2);
    float2 kv = *(const float2*)(k + lane * 2);
    float qq = qv.x * qv.x + qv.y * qv.y;
    float kk = kv.x * kv.x + kv.y * kv.y;
    float qk = qv.x * kv.x + qv.y * kv.y;
    #pragma unroll
    for (int m = 1; m < 64; m <<= 1) {
        qq += __shfl_xor(qq, m);
        kk += __shfl_xor(kk, m);
        qk += __shfl_xor(qk, m);
    }
    if (lane == 0)
        tgt[n] = qk / (fmaxf(sqrtf(qq), EPSN) * fmaxf(sqrtf(kk), EPSN));
}

// ---------------------------------------------------------------------------
// Final: out = mean( log(sums[n]) - tgt[n] )
// ---------------------------------------------------------------------------
__global__ void final_kernel(const float* __restrict__ sums,
                             const float* __restrict__ tgt,
                             float* __restrict__ out)
{
    __shared__ float wsum[4];
    int t = threadIdx.x;
    float acc = 0.f;
    for (int n = t; n < NN; n += 256)
        acc += logf(sums[n]) - tgt[n];
    #pragma unroll
    for (int m = 1; m < 64; m <<= 1) acc += __shfl_xor(acc, m);
    if ((t & 63) == 0) wsum[t >> 6] = acc;
    __syncthreads();
    if (t == 0) out[0] = (wsum[0] + wsum[1] + wsum[2] + wsum[3]) / (float)NN;
}

// ---------------------------------------------------------------------------
extern "C" void kernel_launch(void* const* d_in, const int* in_sizes, int n_in,
                              void* d_out, int out_size, void* d_ws, size_t ws_size,
                              hipStream_t stream)
{
    const float* qemb   = (const float*)d_in[0];
    const float* kemb   = (const float*)d_in[1];
    const int*   loc    = (const int*)d_in[2];
    const int*   labels = (const int*)d_in[3];
    float* out = (float*)d_out;

    char* ws = (char*)d_ws;
    __hip_bfloat16* Kn = (__hip_bfloat16*)ws;
    size_t off = (size_t)NV * D * 2;                       // 25.6 MB
    __hip_bfloat16* Qn = (__hip_bfloat16*)(ws + off);
    off += (size_t)NN * D * 2;                             // +0.5 MB
    float* sums = (float*)(ws + off); off += (size_t)NN * 4;
    float* tgt  = (float*)(ws + off); off += (size_t)NN * 4;

    hipMemsetAsync(sums, 0, NN * sizeof(float), stream);

    {
        int waves  = NV + NN;
        int blocks = (waves + 3) / 4;
        prep_kernel<<<blocks, 256, 0, stream>>>(qemb, kemb, loc, Kn, Qn);
    }
    {
        dim3 grid(8, NSLICE);
        lse_main<<<grid, 256, 0, stream>>>(Kn, Qn, sums);
    }
    tgt_kernel<<<(NN * 64 + 255) / 256, 256, 0, stream>>>(qemb, kemb, loc, labels, tgt);
    final_kernel<<<1, 256, 0, stream>>>(sums, tgt, out);
}

// Round 3
// 284.632 us; speedup vs baseline: 1.3036x; 1.3036x over previous
//
#include <hip/hip_runtime.h>
#include <hip/hip_bf16.h>

typedef __attribute__((ext_vector_type(8))) short short8;
typedef __attribute__((ext_vector_type(4))) float f32x4;

namespace {
constexpr int D    = 128;
constexpr int SEQ  = 512;
constexpr int NV   = 100000;
constexpr int NN   = 2048;
constexpr int KC   = 64;                     // keys per LDS chunk
constexpr int CHUNK_B = KC * D * 2;          // 16384 B
constexpr int NCHUNK  = (NV + KC - 1) / KC;  // 1563
constexpr int CPS     = 13;                  // chunks per V-slice
constexpr int NSLICE  = (NCHUNK + CPS - 1) / CPS;  // 121
constexpr float LOG2E = 1.4426950408889634f;
constexpr float EPSN  = 1e-12f;
}

// ---------------------------------------------------------------------------
// Prep: normalize keys -> bf16 Kn[V][128]; gather+normalize queries scaled by
// log2(e) -> bf16 Qn[N][128]. One wave per row.
// ---------------------------------------------------------------------------
__global__ void prep_kernel(const float* __restrict__ qemb,
                            const float* __restrict__ kemb,
                            const int*   __restrict__ loc,
                            __hip_bfloat16* __restrict__ Kn,
                            __hip_bfloat16* __restrict__ Qn)
{
    int wave = (blockIdx.x * blockDim.x + threadIdx.x) >> 6;
    int lane = threadIdx.x & 63;
    if (wave >= NV + NN) return;

    const float* src;
    __hip_bfloat16* dst;
    float extra;
    if (wave < NV) {
        src = kemb + (size_t)wave * D;
        dst = Kn + (size_t)wave * D;
        extra = 1.0f;
    } else {
        int n = wave - NV;
        int b = loc[2 * n], s = loc[2 * n + 1];
        src = qemb + ((size_t)b * SEQ + s) * D;
        dst = Qn + (size_t)n * D;
        extra = LOG2E;
    }
    float2 v = *(const float2*)(src + lane * 2);
    float ss = v.x * v.x + v.y * v.y;
    #pragma unroll
    for (int m = 1; m < 64; m <<= 1) ss += __shfl_xor(ss, m);
    float inv = extra / fmaxf(sqrtf(ss), EPSN);
    __hip_bfloat162 o;
    o.x = __float2bfloat16(v.x * inv);
    o.y = __float2bfloat16(v.y * inv);
    *(__hip_bfloat162*)(dst + lane * 2) = o;
}

// ---------------------------------------------------------------------------
// Main: per block, 256 Q-rows (4 waves x 64 rows, A-frags in registers ~64
// VGPR/wave), stream keys through double-buffered 64-key LDS chunks staged
// via global_load_lds (linear LDS dest, inverse-swizzled global source).
// Read-side XOR swizzle: phys = logical ^ ((keyrow&7)<<4).
// rowsum += exp2(logit) -> fixed-shift LSE (|logit|<=log2e, no max needed).
// __launch_bounds__(256,3): 170-VGPR budget so the ~130-reg live set
// (qf=64 + acc/rowsum=32 + temps) does NOT spill (r1/r2 lesson: spill was
// 175/542 MB of scratch WRITE_SIZE and the whole perf story).
// ---------------------------------------------------------------------------
__global__ __launch_bounds__(256, 3)
void lse_main(const __hip_bfloat16* __restrict__ Kn,
              const __hip_bfloat16* __restrict__ Qn,
              float* __restrict__ sums)
{
    __shared__ char lds[2 * CHUNK_B];   // 32 KB
    const int tid  = threadIdx.x;
    const int lane = tid & 63;
    const int lr   = lane & 15;
    const int lh   = lane >> 4;
    const int w    = tid >> 6;
    const int mblk  = blockIdx.x;   // 0..7
    const int slice = blockIdx.y;   // 0..NSLICE-1

    const int chunk0 = slice * CPS;
    const int nch = min(CPS, NCHUNK - chunk0);
    const int m0 = mblk * 256 + w * 64;
    const char* kbase = (const char*)Kn;

    // async stage of chunk c into buffer bi: LDS linear, source pre-swizzled
    auto stage = [&](int c, int bi) {
        const int keybase = (chunk0 + c) * KC;
        #pragma unroll
        for (int r = 0; r < 4; ++r) {
            const int i   = w * 4 + r;          // 1KB-slab index, wave-uniform
            const int kic = i * 4 + lh;         // key row within chunk (per-lane)
            const int key = min(keybase + kic, NV - 1);
            const int sb  = (lr ^ (kic & 7)) << 4;   // inverse-swizzled byte-in-row
            const char* g = kbase + (size_t)key * 256 + sb;
            const char* l = lds + bi * CHUNK_B + i * 1024;  // wave-uniform base
            __builtin_amdgcn_global_load_lds(
                (const __attribute__((address_space(1))) void*)g,
                (__attribute__((address_space(3))) void*)l, 16, 0, 0);
        }
    };

    stage(0, 0);   // prologue: in flight while we fetch Q fragments

    // A-operand (Q) fragments: rows m0+rg*16+lr, k = ds*32 + lh*8 .. +8
    short8 qf[4][4];
    #pragma unroll
    for (int rg = 0; rg < 4; ++rg)
        #pragma unroll
        for (int ds = 0; ds < 4; ++ds)
            qf[rg][ds] = *(const short8*)((const short*)Qn +
                          (size_t)(m0 + rg * 16 + lr) * D + ds * 32 + lh * 8);

    float rowsum[4][4] = {};
    __syncthreads();   // drains prologue glds (vmcnt) + barrier

    int cur = 0;
    for (int c = 0; c < nch; ++c) {
        if (c + 1 < nch) stage(c + 1, cur ^ 1);   // issue early (T14 / T3-min)

        const char* buf = lds + cur * CHUNK_B;
        const int vbase = (chunk0 + c) * KC;
        const bool full = (vbase + KC <= NV);
        #pragma unroll
        for (int kg = 0; kg < 4; ++kg) {
            const int kic = kg * 16 + lr;       // key row within chunk
            const int rx  = (kic & 7) << 4;
            f32x4 acc[4] = {{0,0,0,0},{0,0,0,0},{0,0,0,0},{0,0,0,0}};
            #pragma unroll
            for (int ds2 = 0; ds2 < 4; ++ds2) {
                short8 bf = *(const short8*)(buf +
                              ((kic * 256 + ds2 * 64 + lh * 16) ^ rx));
                #pragma unroll
                for (int rg = 0; rg < 4; ++rg)
                    acc[rg] = __builtin_amdgcn_mfma_f32_16x16x32_bf16(
                                  qf[rg][ds2], bf, acc[rg], 0, 0, 0);
            }
            if (full) {
                #pragma unroll
                for (int rg = 0; rg < 4; ++rg)
                    #pragma unroll
                    for (int j = 0; j < 4; ++j)
                        rowsum[rg][j] += __builtin_amdgcn_exp2f(acc[rg][j]);
            } else {
                const bool ok = (vbase + kic) < NV;   // col = lr on output
                #pragma unroll
                for (int rg = 0; rg < 4; ++rg)
                    #pragma unroll
                    for (int j = 0; j < 4; ++j)
                        rowsum[rg][j] += ok ? __builtin_amdgcn_exp2f(acc[rg][j]) : 0.f;
            }
        }
        __syncthreads();   // drains stage's vmcnt + protects buffer swap
        cur ^= 1;
    }

    // reduce partial sums across the 16 column-lanes, one atomic per row
    #pragma unroll
    for (int rg = 0; rg < 4; ++rg)
        #pragma unroll
        for (int j = 0; j < 4; ++j) {
            float v = rowsum[rg][j];
            v += __shfl_xor(v, 1);
            v += __shfl_xor(v, 2);
            v += __shfl_xor(v, 4);
            v += __shfl_xor(v, 8);
            if (lr == 0)
                atomicAdd(&sums[m0 + rg * 16 + lh * 4 + j], v);
        }
}

// ---------------------------------------------------------------------------
// tgt[n] = <q_n, k_label>/(|q_n||k_label|) in full fp32. One wave per n.
// ---------------------------------------------------------------------------
__global__ void tgt_kernel(const float* __restrict__ qemb,
                           const float* __restrict__ kemb,
                           const int*   __restrict__ loc,
                           const int*   __restrict__ labels,
                           float* __restrict__ tgt)
{
    int n = (blockIdx.x * blockDim.x + threadIdx.x) >> 6;
    int lane = threadIdx.x & 63;
    if (n >= NN) return;
    int b = loc[2 * n], s = loc[2 * n + 1];
    const float* q = qemb + ((size_t)b * SEQ + s) * D;
    const float* k = kemb + (size_t)labels[n] * D;
    float2 qv = *(const float2*)(q + lane * 2);
    float2 kv = *(const float2*)(k + lane * 2);
    float qq = qv.x * qv.x + qv.y * qv.y;
    float kk = kv.x * kv.x + kv.y * kv.y;
    float qk = qv.x * kv.x + qv.y * kv.y;
    #pragma unroll
    for (int m = 1; m < 64; m <<= 1) {
        qq += __shfl_xor(qq, m);
        kk += __shfl_xor(kk, m);
        qk += __shfl_xor(qk, m);
    }
    if (lane == 0)
        tgt[n] = qk / (fmaxf(sqrtf(qq), EPSN) * fmaxf(sqrtf(kk), EPSN));
}

// ---------------------------------------------------------------------------
// Final: out = mean( log(sums[n]) - tgt[n] )
// ---------------------------------------------------------------------------
__global__ void final_kernel(const float* __restrict__ sums,
                             const float* __restrict__ tgt,
                             float* __restrict__ out)
{
    __shared__ float wsum[4];
    int t = threadIdx.x;
    float acc = 0.f;
    for (int n = t; n < NN; n += 256)
        acc += logf(sums[n]) - tgt[n];
    #pragma unroll
    for (int m = 1; m < 64; m <<= 1) acc += __shfl_xor(acc, m);
    if ((t & 63) == 0) wsum[t >> 6] = acc;
    __syncthreads();
    if (t == 0) out[0] = (wsum[0] + wsum[1] + wsum[2] + wsum[3]) / (float)NN;
}

// ---------------------------------------------------------------------------
extern "C" void kernel_launch(void* const* d_in, const int* in_sizes, int n_in,
                              void* d_out, int out_size, void* d_ws, size_t ws_size,
                              hipStream_t stream)
{
    const float* qemb   = (const float*)d_in[0];
    const float* kemb   = (const float*)d_in[1];
    const int*   loc    = (const int*)d_in[2];
    const int*   labels = (const int*)d_in[3];
    float* out = (float*)d_out;

    char* ws = (char*)d_ws;
    __hip_bfloat16* Kn = (__hip_bfloat16*)ws;
    size_t off = (size_t)NV * D * 2;                       // 25.6 MB
    __hip_bfloat16* Qn = (__hip_bfloat16*)(ws + off);
    off += (size_t)NN * D * 2;                             // +0.5 MB
    float* sums = (float*)(ws + off); off += (size_t)NN * 4;
    float* tgt  = (float*)(ws + off); off += (size_t)NN * 4;

    hipMemsetAsync(sums, 0, NN * sizeof(float), stream);

    {
        int waves  = NV + NN;
        int blocks = (waves + 3) / 4;
        prep_kernel<<<blocks, 256, 0, stream>>>(qemb, kemb, loc, Kn, Qn);
    }
    {
        dim3 grid(8, NSLICE);
        lse_main<<<grid, 256, 0, stream>>>(Kn, Qn, sums);
    }
    tgt_kernel<<<(NN * 64 + 255) / 256, 256, 0, stream>>>(qemb, kemb, loc, labels, tgt);
    final_kernel<<<1, 256, 0, stream>>>(sums, tgt, out);
}

// Round 4
// 167.782 us; speedup vs baseline: 2.2115x; 1.6964x over previous
//
#include <hip/hip_runtime.h>
#include <hip/hip_bf16.h>

typedef __attribute__((ext_vector_type(8))) short short8;
typedef __attribute__((ext_vector_type(4))) float f32x4;

namespace {
constexpr int D    = 128;
constexpr int SEQ  = 512;
constexpr int NV   = 100000;
constexpr int NN   = 2048;
constexpr int KC   = 64;                     // keys per LDS chunk
constexpr int CHUNK_B = KC * D * 2;          // 16384 B
constexpr int NCHUNK  = (NV + KC - 1) / KC;  // 1563
constexpr int CPS     = 13;                  // chunks per V-slice
constexpr int NSLICE  = (NCHUNK + CPS - 1) / CPS;  // 121
constexpr int MBLKS   = 8;                   // M blocks of 256 rows
constexpr float LOG2E = 1.4426950408889634f;
constexpr float EPSN  = 1e-12f;
}

// ---------------------------------------------------------------------------
// Prep: normalize keys -> bf16 Kn[V][128]; gather+normalize queries scaled by
// log2(e) -> bf16 Qn[N][128]. One wave per row.
// ---------------------------------------------------------------------------
__global__ void prep_kernel(const float* __restrict__ qemb,
                            const float* __restrict__ kemb,
                            const int*   __restrict__ loc,
                            __hip_bfloat16* __restrict__ Kn,
                            __hip_bfloat16* __restrict__ Qn)
{
    int wave = (blockIdx.x * blockDim.x + threadIdx.x) >> 6;
    int lane = threadIdx.x & 63;
    if (wave >= NV + NN) return;

    const float* src;
    __hip_bfloat16* dst;
    float extra;
    if (wave < NV) {
        src = kemb + (size_t)wave * D;
        dst = Kn + (size_t)wave * D;
        extra = 1.0f;
    } else {
        int n = wave - NV;
        int b = loc[2 * n], s = loc[2 * n + 1];
        src = qemb + ((size_t)b * SEQ + s) * D;
        dst = Qn + (size_t)n * D;
        extra = LOG2E;
    }
    float2 v = *(const float2*)(src + lane * 2);
    float ss = v.x * v.x + v.y * v.y;
    #pragma unroll
    for (int m = 1; m < 64; m <<= 1) ss += __shfl_xor(ss, m);
    float inv = extra / fmaxf(sqrtf(ss), EPSN);
    __hip_bfloat162 o;
    o.x = __float2bfloat16(v.x * inv);
    o.y = __float2bfloat16(v.y * inv);
    *(__hip_bfloat162*)(dst + lane * 2) = o;
}

// ---------------------------------------------------------------------------
// Main. 512 threads = 8 waves; each wave owns 32 Q-rows (qf[2][4] = 32 VGPR
// -> per-wave live set ~80 regs, NO spill at the 128-VGPR budget of
// __launch_bounds__(512,4); r1-r3 lesson: spill WRITE_SIZE was the story).
// Block covers 256 rows x one 13-chunk key slice; keys stream through
// double-buffered 64-key LDS chunks via global_load_lds (linear LDS dest,
// inverse-swizzled global source; read phys = logical ^ ((keyrow&7)<<4)).
// XCD swizzle: same-slice blocks co-located per XCD so K is HBM-fetched
// once (~26 MB) and re-served from that XCD's L2 (slice K = 208 KB).
// rowsum += exp2(logit): |logit|<=log2e -> fixed-shift LSE, no running max.
// ---------------------------------------------------------------------------
__global__ __launch_bounds__(512, 4)
void lse_main(const __hip_bfloat16* __restrict__ Kn,
              const __hip_bfloat16* __restrict__ Qn,
              float* __restrict__ sums)
{
    __shared__ char lds[2 * CHUNK_B];   // 32 KB
    const int tid  = threadIdx.x;
    const int lane = tid & 63;
    const int lr   = lane & 15;
    const int lh   = lane >> 4;
    const int w    = tid >> 6;          // wave 0..7

    // XCD-aware decode: XCD k processes lin in [121k, 121k+121) -> the 8
    // mblk-blocks of a slice run on the SAME XCD (K L2-resident there).
    const int bid = blockIdx.x;
    const int lin = (bid & 7) * NSLICE + (bid >> 3);
    const int slice = lin >> 3;
    const int mblk  = lin & 7;

    const int chunk0 = slice * CPS;
    const int nch = min(CPS, NCHUNK - chunk0);
    const int m0 = mblk * 256 + w * 32;
    const char* kbase = (const char*)Kn;

    // async stage of chunk c into buffer bi: LDS linear, source pre-swizzled
    auto stage = [&](int c, int bi) {
        const int keybase = (chunk0 + c) * KC;
        #pragma unroll
        for (int r = 0; r < 2; ++r) {
            const int i   = w * 2 + r;          // 1KB-slab index, wave-uniform
            const int kic = i * 4 + lh;         // key row within chunk (per-lane)
            const int key = min(keybase + kic, NV - 1);
            const int sb  = (lr ^ (kic & 7)) << 4;   // inverse-swizzled byte-in-row
            const char* g = kbase + (size_t)key * 256 + sb;
            const char* l = lds + bi * CHUNK_B + i * 1024;  // wave-uniform base
            __builtin_amdgcn_global_load_lds(
                (const __attribute__((address_space(1))) void*)g,
                (__attribute__((address_space(3))) void*)l, 16, 0, 0);
        }
    };

    stage(0, 0);   // prologue: in flight while we fetch Q fragments

    // A-operand (Q) fragments: rows m0+rg*16+lr, k = ds*32 + lh*8 .. +8
    short8 qf[2][4];
    #pragma unroll
    for (int rg = 0; rg < 2; ++rg)
        #pragma unroll
        for (int ds = 0; ds < 4; ++ds)
            qf[rg][ds] = *(const short8*)((const short*)Qn +
                          (size_t)(m0 + rg * 16 + lr) * D + ds * 32 + lh * 8);

    float rowsum[2][4] = {};
    __syncthreads();   // drains prologue glds (vmcnt) + barrier

    int cur = 0;
    for (int c = 0; c < nch; ++c) {
        if (c + 1 < nch) stage(c + 1, cur ^ 1);   // issue early (T14)

        const char* buf = lds + cur * CHUNK_B;
        const int vbase = (chunk0 + c) * KC;
        const bool full = (vbase + KC <= NV);
        #pragma unroll
        for (int kg = 0; kg < 4; ++kg) {
            const int kic = kg * 16 + lr;       // key row within chunk
            const int rx  = (kic & 7) << 4;
            f32x4 acc[2] = {{0,0,0,0},{0,0,0,0}};
            #pragma unroll
            for (int ds2 = 0; ds2 < 4; ++ds2) {
                short8 bf = *(const short8*)(buf +
                              ((kic * 256 + ds2 * 64 + lh * 16) ^ rx));
                #pragma unroll
                for (int rg = 0; rg < 2; ++rg)
                    acc[rg] = __builtin_amdgcn_mfma_f32_16x16x32_bf16(
                                  qf[rg][ds2], bf, acc[rg], 0, 0, 0);
            }
            if (full) {
                #pragma unroll
                for (int rg = 0; rg < 2; ++rg)
                    #pragma unroll
                    for (int j = 0; j < 4; ++j)
                        rowsum[rg][j] += __builtin_amdgcn_exp2f(acc[rg][j]);
            } else {
                const bool ok = (vbase + kic) < NV;   // col = lr on output
                #pragma unroll
                for (int rg = 0; rg < 2; ++rg)
                    #pragma unroll
                    for (int j = 0; j < 4; ++j)
                        rowsum[rg][j] += ok ? __builtin_amdgcn_exp2f(acc[rg][j]) : 0.f;
            }
        }
        __syncthreads();   // drains stage's vmcnt + protects buffer swap
        cur ^= 1;
    }

    // reduce partial sums across the 16 column-lanes, one atomic per row
    #pragma unroll
    for (int rg = 0; rg < 2; ++rg)
        #pragma unroll
        for (int j = 0; j < 4; ++j) {
            float v = rowsum[rg][j];
            v += __shfl_xor(v, 1);
            v += __shfl_xor(v, 2);
            v += __shfl_xor(v, 4);
            v += __shfl_xor(v, 8);
            if (lr == 0)
                atomicAdd(&sums[m0 + rg * 16 + lh * 4 + j], v);
        }
}

// ---------------------------------------------------------------------------
// tgt[n] = <q_n, k_label>/(|q_n||k_label|) in full fp32. One wave per n.
// ---------------------------------------------------------------------------
__global__ void tgt_kernel(const float* __restrict__ qemb,
                           const float* __restrict__ kemb,
                           const int*   __restrict__ loc,
                           const int*   __restrict__ labels,
                           float* __restrict__ tgt)
{
    int n = (blockIdx.x * blockDim.x + threadIdx.x) >> 6;
    int lane = threadIdx.x & 63;
    if (n >= NN) return;
    int b = loc[2 * n], s = loc[2 * n + 1];
    const float* q = qemb + ((size_t)b * SEQ + s) * D;
    const float* k = kemb + (size_t)labels[n] * D;
    float2 qv = *(const float2*)(q + lane * 2);
    float2 kv = *(const float2*)(k + lane * 2);
    float qq = qv.x * qv.x + qv.y * qv.y;
    float kk = kv.x * kv.x + kv.y * kv.y;
    float qk = qv.x * kv.x + qv.y * kv.y;
    #pragma unroll
    for (int m = 1; m < 64; m <<= 1) {
        qq += __shfl_xor(qq, m);
        kk += __shfl_xor(kk, m);
        qk += __shfl_xor(qk, m);
    }
    if (lane == 0)
        tgt[n] = qk / (fmaxf(sqrtf(qq), EPSN) * fmaxf(sqrtf(kk), EPSN));
}

// ---------------------------------------------------------------------------
// Final: out = mean( log(sums[n]) - tgt[n] )
// ---------------------------------------------------------------------------
__global__ void final_kernel(const float* __restrict__ sums,
                             const float* __restrict__ tgt,
                             float* __restrict__ out)
{
    __shared__ float wsum[4];
    int t = threadIdx.x;
    float acc = 0.f;
    for (int n = t; n < NN; n += 256)
        acc += logf(sums[n]) - tgt[n];
    #pragma unroll
    for (int m = 1; m < 64; m <<= 1) acc += __shfl_xor(acc, m);
    if ((t & 63) == 0) wsum[t >> 6] = acc;
    __syncthreads();
    if (t == 0) out[0] = (wsum[0] + wsum[1] + wsum[2] + wsum[3]) / (float)NN;
}

// ---------------------------------------------------------------------------
extern "C" void kernel_launch(void* const* d_in, const int* in_sizes, int n_in,
                              void* d_out, int out_size, void* d_ws, size_t ws_size,
                              hipStream_t stream)
{
    const float* qemb   = (const float*)d_in[0];
    const float* kemb   = (const float*)d_in[1];
    const int*   loc    = (const int*)d_in[2];
    const int*   labels = (const int*)d_in[3];
    float* out = (float*)d_out;

    char* ws = (char*)d_ws;
    __hip_bfloat16* Kn = (__hip_bfloat16*)ws;
    size_t off = (size_t)NV * D * 2;                       // 25.6 MB
    __hip_bfloat16* Qn = (__hip_bfloat16*)(ws + off);
    off += (size_t)NN * D * 2;                             // +0.5 MB
    float* sums = (float*)(ws + off); off += (size_t)NN * 4;
    float* tgt  = (float*)(ws + off); off += (size_t)NN * 4;

    hipMemsetAsync(sums, 0, NN * sizeof(float), stream);

    {
        int waves  = NV + NN;
        int blocks = (waves + 3) / 4;
        prep_kernel<<<blocks, 256, 0, stream>>>(qemb, kemb, loc, Kn, Qn);
    }
    lse_main<<<MBLKS * NSLICE, 512, 0, stream>>>(Kn, Qn, sums);
    tgt_kernel<<<(NN * 64 + 255) / 256, 256, 0, stream>>>(qemb, kemb, loc, labels, tgt);
    final_kernel<<<1, 256, 0, stream>>>(sums, tgt, out);
}

// Round 5
// 161.049 us; speedup vs baseline: 2.3040x; 1.0418x over previous
//
#include <hip/hip_runtime.h>
#include <hip/hip_bf16.h>

typedef __attribute__((ext_vector_type(8))) short short8;
typedef __attribute__((ext_vector_type(4))) short short4v;
typedef __attribute__((ext_vector_type(4))) float f32x4;

namespace {
constexpr int D    = 128;
constexpr int SEQ  = 512;
constexpr int NV   = 100000;
constexpr int NN   = 2048;
constexpr int KC   = 64;                     // keys per LDS chunk
constexpr int CHUNK_B = KC * D * 2;          // 16384 B
constexpr int NCHUNK  = (NV + KC - 1) / KC;  // 1563
constexpr int CPS     = 17;                  // chunks per V-slice
constexpr int NSLICE  = (NCHUNK + CPS - 1) / CPS;  // 92
constexpr int MBLKS   = 8;                   // M blocks of 256 rows
constexpr float LOG2E = 1.4426950408889634f;
constexpr float EPSN  = 1e-12f;
}

// ---------------------------------------------------------------------------
// Prep: normalize keys -> bf16 Kn[V][128]; gather+normalize queries scaled by
// log2(e) -> bf16 Qn[N][128]. TWO rows per wave (32 lanes/row, float4 loads
// = 16B/lane, 8B/lane stores) -- r4 lesson: the old wave-per-row 8B/lane
// version was the prime suspect for ~60+ us of "other" time.
// ---------------------------------------------------------------------------
__global__ __launch_bounds__(256)
void prep_kernel(const float* __restrict__ qemb,
                 const float* __restrict__ kemb,
                 const int*   __restrict__ loc,
                 __hip_bfloat16* __restrict__ Kn,
                 __hip_bfloat16* __restrict__ Qn)
{
    const int gw   = (blockIdx.x * blockDim.x + threadIdx.x) >> 6;
    const int lane = threadIdx.x & 63;
    const int half = lane >> 5;          // 0/1: which of the wave's 2 rows
    const int l32  = lane & 31;
    const int row  = gw * 2 + half;      // NV is even -> no K/Q straddle
    if (row >= NV + NN) return;

    const float* src;
    __hip_bfloat16* dst;
    float extra;
    if (row < NV) {
        src = kemb + (size_t)row * D;
        dst = Kn + (size_t)row * D;
        extra = 1.0f;
    } else {
        int n = row - NV;
        int b = loc[2 * n], s = loc[2 * n + 1];
        src = qemb + ((size_t)b * SEQ + s) * D;
        dst = Qn + (size_t)n * D;
        extra = LOG2E;
    }
    float4 v = *(const float4*)(src + l32 * 4);
    float ss = v.x * v.x + v.y * v.y + v.z * v.z + v.w * v.w;
    #pragma unroll
    for (int m = 1; m < 32; m <<= 1) ss += __shfl_xor(ss, m);  // half-wave sum
    float inv = extra / fmaxf(sqrtf(ss), EPSN);

    union { __hip_bfloat162 h2[2]; short4v s4; } u;
    u.h2[0].x = __float2bfloat16(v.x * inv);
    u.h2[0].y = __float2bfloat16(v.y * inv);
    u.h2[1].x = __float2bfloat16(v.z * inv);
    u.h2[1].y = __float2bfloat16(v.w * inv);
    *(short4v*)((char*)dst + l32 * 8) = u.s4;
}

// ---------------------------------------------------------------------------
// Main. 512 threads = 8 waves; each wave owns 32 Q-rows (qf[2][4] = 32 VGPR,
// ~70-reg live set, no spill -- r1-r3 lesson). Block covers 256 rows x one
// 17-chunk key slice. Keys stream through a 3-buffer LDS ring (48 KB) with
// DEPTH-2 prefetch via global_load_lds (linear LDS dest, inverse-swizzled
// global source; read phys = logical ^ ((keyrow&7)<<4)).
// Counted s_waitcnt vmcnt(2) + raw s_barrier per chunk (T3/T4-lite): the
// awaited stage was issued a full iteration earlier, so the old
// __syncthreads vmcnt(0) drain stall disappears.
// Grid = 8*92 = 736 <= 3 blocks/CU * 256 CU = 768 -> single residency
// generation. XCD swizzle keeps a slice's 8 M-blocks on one XCD (K fetched
// from HBM once; r4: FETCH 208->15 MB).
// rowsum += exp2(logit): |logit|<=log2e -> fixed-shift LSE, no running max.
// ---------------------------------------------------------------------------
__global__ __launch_bounds__(512, 4)
void lse_main(const __hip_bfloat16* __restrict__ Kn,
              const __hip_bfloat16* __restrict__ Qn,
              float* __restrict__ sums)
{
    __shared__ char lds[3 * CHUNK_B];   // 48 KB -> 3 blocks/CU
    const int tid  = threadIdx.x;
    const int lane = tid & 63;
    const int lr   = lane & 15;
    const int lh   = lane >> 4;
    const int w    = tid >> 6;          // wave 0..7

    // XCD-aware decode: XCD k owns lin in [92k, 92k+92) -> a slice's 8
    // mblk-blocks run on (nearly always) the same XCD.
    const int bid = blockIdx.x;
    const int lin = (bid & 7) * NSLICE + (bid >> 3);
    const int slice = lin >> 3;
    const int mblk  = lin & 7;

    const int chunk0 = slice * CPS;
    const int nch = min(CPS, NCHUNK - chunk0);
    const int m0 = mblk * 256 + w * 32;
    const char* kbase = (const char*)Kn;

    // async stage of chunk c into ring buffer bi: LDS linear dest,
    // source pre-swizzled (rule #21: both-sides-or-neither).
    auto stage = [&](int c, int bi) {
        const int keybase = (chunk0 + c) * KC;
        #pragma unroll
        for (int r = 0; r < 2; ++r) {
            const int i   = w * 2 + r;          // 1KB-slab index, wave-uniform
            const int kic = i * 4 + lh;         // key row within chunk (per-lane)
            const int key = min(keybase + kic, NV - 1);
            const int sb  = (lr ^ (kic & 7)) << 4;   // inverse-swizzled byte-in-row
            const char* g = kbase + (size_t)key * 256 + sb;
            const char* l = lds + bi * CHUNK_B + i * 1024;  // wave-uniform base
            __builtin_amdgcn_global_load_lds(
                (const __attribute__((address_space(1))) void*)g,
                (__attribute__((address_space(3))) void*)l, 16, 0, 0);
        }
    };

    stage(0, 0);                       // prologue depth-2
    if (nch > 1) stage(1, 1);

    // A-operand (Q) fragments: rows m0+rg*16+lr, k = ds*32 + lh*8 .. +8
    short8 qf[2][4];
    #pragma unroll
    for (int rg = 0; rg < 2; ++rg)
        #pragma unroll
        for (int ds = 0; ds < 4; ++ds)
            qf[rg][ds] = *(const short8*)((const short*)Qn +
                          (size_t)(m0 + rg * 16 + lr) * D + ds * 32 + lh * 8);

    float rowsum[2][4] = {};
    __syncthreads();   // one-time full drain (prologue stages + qf)

    for (int c = 0; c < nch; ++c) {
        if (c + 2 < nch) stage(c + 2, (c + 2) % 3);   // depth-2 prefetch

        const char* buf = lds + (c % 3) * CHUNK_B;
        const int vbase = (chunk0 + c) * KC;
        const bool full = (vbase + KC <= NV);
        #pragma unroll
        for (int kg = 0; kg < 4; ++kg) {
            const int kic = kg * 16 + lr;       // key row within chunk
            const int rx  = (kic & 7) << 4;
            f32x4 acc[2] = {{0,0,0,0},{0,0,0,0}};
            #pragma unroll
            for (int ds2 = 0; ds2 < 4; ++ds2) {
                short8 bf = *(const short8*)(buf +
                              ((kic * 256 + ds2 * 64 + lh * 16) ^ rx));
                #pragma unroll
                for (int rg = 0; rg < 2; ++rg)
                    acc[rg] = __builtin_amdgcn_mfma_f32_16x16x32_bf16(
                                  qf[rg][ds2], bf, acc[rg], 0, 0, 0);
            }
            if (full) {
                #pragma unroll
                for (int rg = 0; rg < 2; ++rg)
                    #pragma unroll
                    for (int j = 0; j < 4; ++j)
                        rowsum[rg][j] += __builtin_amdgcn_exp2f(acc[rg][j]);
            } else {
                const bool ok = (vbase + kic) < NV;   // col = lr on output
                #pragma unroll
                for (int rg = 0; rg < 2; ++rg)
                    #pragma unroll
                    for (int j = 0; j < 4; ++j)
                        rowsum[rg][j] += ok ? __builtin_amdgcn_exp2f(acc[rg][j]) : 0.f;
            }
        }
        // counted wait: stage(c+1) (issued LAST iteration) must be done;
        // stage(c+2)'s 2 loads may stay in flight across the barrier (T4).
        asm volatile("s_waitcnt vmcnt(2)" ::: "memory");
        __builtin_amdgcn_s_barrier();
        asm volatile("" ::: "memory");
    }

    // reduce partial sums across the 16 column-lanes, one atomic per row
    #pragma unroll
    for (int rg = 0; rg < 2; ++rg)
        #pragma unroll
        for (int j = 0; j < 4; ++j) {
            float v = rowsum[rg][j];
            v += __shfl_xor(v, 1);
            v += __shfl_xor(v, 2);
            v += __shfl_xor(v, 4);
            v += __shfl_xor(v, 8);
            if (lr == 0)
                atomicAdd(&sums[m0 + rg * 16 + lh * 4 + j], v);
        }
}

// ---------------------------------------------------------------------------
// tgt[n] = <q_n, k_label>/(|q_n||k_label|) in full fp32. One wave per n.
// ---------------------------------------------------------------------------
__global__ void tgt_kernel(const float* __restrict__ qemb,
                           const float* __restrict__ kemb,
                           const int*   __restrict__ loc,
                           const int*   __restrict__ labels,
                           float* __restrict__ tgt)
{
    int n = (blockIdx.x * blockDim.x + threadIdx.x) >> 6;
    int lane = threadIdx.x & 63;
    if (n >= NN) return;
    int b = loc[2 * n], s = loc[2 * n + 1];
    const float* q = qemb + ((size_t)b * SEQ + s) * D;
    const float* k = kemb + (size_t)labels[n] * D;
    float2 qv = *(const float2*)(q + lane * 2);
    float2 kv = *(const float2*)(k + lane * 2);
    float qq = qv.x * qv.x + qv.y * qv.y;
    float kk = kv.x * kv.x + kv.y * kv.y;
    float qk = qv.x * kv.x + qv.y * kv.y;
    #pragma unroll
    for (int m = 1; m < 64; m <<= 1) {
        qq += __shfl_xor(qq, m);
        kk += __shfl_xor(kk, m);
        qk += __shfl_xor(qk, m);
    }
    if (lane == 0)
        tgt[n] = qk / (fmaxf(sqrtf(qq), EPSN) * fmaxf(sqrtf(kk), EPSN));
}

// ---------------------------------------------------------------------------
// Final: out = mean( log(sums[n]) - tgt[n] )
// ---------------------------------------------------------------------------
__global__ void final_kernel(const float* __restrict__ sums,
                             const float* __restrict__ tgt,
                             float* __restrict__ out)
{
    __shared__ float wsum[4];
    int t = threadIdx.x;
    float acc = 0.f;
    for (int n = t; n < NN; n += 256)
        acc += logf(sums[n]) - tgt[n];
    #pragma unroll
    for (int m = 1; m < 64; m <<= 1) acc += __shfl_xor(acc, m);
    if ((t & 63) == 0) wsum[t >> 6] = acc;
    __syncthreads();
    if (t == 0) out[0] = (wsum[0] + wsum[1] + wsum[2] + wsum[3]) / (float)NN;
}

// ---------------------------------------------------------------------------
extern "C" void kernel_launch(void* const* d_in, const int* in_sizes, int n_in,
                              void* d_out, int out_size, void* d_ws, size_t ws_size,
                              hipStream_t stream)
{
    const float* qemb   = (const float*)d_in[0];
    const float* kemb   = (const float*)d_in[1];
    const int*   loc    = (const int*)d_in[2];
    const int*   labels = (const int*)d_in[3];
    float* out = (float*)d_out;

    char* ws = (char*)d_ws;
    __hip_bfloat16* Kn = (__hip_bfloat16*)ws;
    size_t off = (size_t)NV * D * 2;                       // 25.6 MB
    __hip_bfloat16* Qn = (__hip_bfloat16*)(ws + off);
    off += (size_t)NN * D * 2;                             // +0.5 MB
    float* sums = (float*)(ws + off); off += (size_t)NN * 4;
    float* tgt  = (float*)(ws + off); off += (size_t)NN * 4;

    hipMemsetAsync(sums, 0, NN * sizeof(float), stream);

    {
        int waves  = (NV + NN + 1) / 2;        // 2 rows per wave
        int blocks = (waves + 3) / 4;
        prep_kernel<<<blocks, 256, 0, stream>>>(qemb, kemb, loc, Kn, Qn);
    }
    lse_main<<<MBLKS * NSLICE, 512, 0, stream>>>(Kn, Qn, sums);
    tgt_kernel<<<(NN * 64 + 255) / 256, 256, 0, stream>>>(qemb, kemb, loc, labels, tgt);
    final_kernel<<<1, 256, 0, stream>>>(sums, tgt, out);
}